// Round 1
// baseline (465.639 us; speedup 1.0000x reference)
//
#include <hip/hip_runtime.h>
#include <cstdint>
#include <cstddef>

#define BATCH  8192
#define IN_N   256
#define OUT_N  256
#define LAT_N  128
#define SLABS  129                 // 128 latent slabs + 1 bw slab
#define KT     (SLABS * IN_N)      // 33024 = total K in elements
#define KT16   (KT / 16)           // 2064 k-tiles of 16
#define SPLITK 8

typedef _Float16 h8 __attribute__((ext_vector_type(8)));
typedef _Float16 h4 __attribute__((ext_vector_type(4)));
typedef float    f16v __attribute__((ext_vector_type(16)));

// ws layout (bytes)
#define WS_BP    0                 // packed B: 8 nt * 2064 kt * 64 lane * 8 halves * 2B = 16908288
#define WS_XH    16908288          // + 8192*256*2 = 4194304
#define WS_LT    21102592          // + 129*8192*2 = 2113536
// total = 23216128 bytes (no parts buffers anymore)

// ---------------- K1: build B in MFMA-fragment-packed order.
// Bp[nt][kt16][lane][h]  (lane = kh*32 + n32, h = 0..7)
//   = W2T[o = nt*32 + n32][k = kt16*16 + kh*8 + h]
// where W2T[o][k] = k<32768 ? Ww[k*256+o] : bw[(k-32768)*256+o]
// A wave's B-fragment load in k_gemm is then one contiguous 1KB dwordx4.
__global__ void k_transpose(const float* __restrict__ Ww, const float* __restrict__ bw,
                            _Float16* __restrict__ Bp) {
    __shared__ float tile[64][65];
    const int k0 = blockIdx.x * 64;    // 516 tiles along k (516*64 = 33024)
    const int o0 = blockIdx.y * 64;    // 4 tiles along o
    const int t  = threadIdx.x;        // 256 threads
    const int c  = t & 63, r0 = t >> 6;
#pragma unroll
    for (int j = 0; j < 16; ++j) {
        int r = r0 + 4 * j;
        int k = k0 + r;
        float v;
        if (k < LAT_N * IN_N) v = Ww[(size_t)k * 256 + o0 + c];
        else                  v = bw[(size_t)(k - LAT_N * IN_N) * 256 + o0 + c];
        tile[r][c] = v;               // tile[k - k0][o - o0]
    }
    __syncthreads();
    // pack phase: 8 subtiles of [16k x 32o]; subtile st handled by threads st*32..st*32+31
    const int tl = t & 31, st = t >> 5;
    const int kt_l = st >> 1, nt_l = st & 1;
    const int nt   = blockIdx.y * 2 + kt_l * 0 + nt_l;   // 0..7
    const int kt16 = blockIdx.x * 4 + kt_l;              // 0..2063
    _Float16* dst = Bp + ((size_t)(nt * KT16 + kt16) * 64) * 8;
#pragma unroll
    for (int kh = 0; kh < 2; ++kh) {
        h8 v;
#pragma unroll
        for (int h = 0; h < 8; ++h)
            v[h] = (_Float16)tile[kt_l * 16 + kh * 8 + h][nt_l * 32 + tl];
        *(h8*)(dst + (size_t)(kh * 32 + tl) * 8) = v;
    }
}

// ---------------- K2: x -> f16, latent -> LT[l][b] f16 (+ ones row l=128)
__global__ void k_convert(const float* __restrict__ x, const float* __restrict__ latent,
                          _Float16* __restrict__ Xh, _Float16* __restrict__ LT) {
    const int bid = blockIdx.x;
    if (bid < 2048) {                       // x: 2M elems, 4 per thread
        int i = (bid * 256 + threadIdx.x) * 4;
        float4 v = *(const float4*)(x + i);
        h4 o;
        o[0] = (_Float16)v.x; o[1] = (_Float16)v.y;
        o[2] = (_Float16)v.z; o[3] = (_Float16)v.w;
        *(h4*)(Xh + i) = o;
    } else if (bid < 2048 + 4096) {         // latent transpose: 1M elems
        int i = (bid - 2048) * 256 + threadIdx.x;
        int b = i >> 7, l = i & 127;
        LT[(size_t)l * BATCH + b] = (_Float16)latent[i];
    } else {                                // ones row: 8192 elems
        int b = (bid - 2048 - 4096) * 256 + threadIdx.x;
        LT[(size_t)LAT_N * BATCH + b] = (_Float16)1.0f;
    }
}

// ---------------- K3: out[b][o] = latent[b]·Wb[:,o] + bb[o]  (bias written straight to out;
//                     k_gemm then atomically accumulates the GEMM on top)
__global__ void k_bias(const float* __restrict__ latent, const float* __restrict__ Wb,
                       const float* __restrict__ bb, float* __restrict__ out) {
    __shared__ float lat[8][128];
    const int b0 = blockIdx.x * 8;          // 1024 blocks
    const int t = threadIdx.x;
#pragma unroll
    for (int j = 0; j < 4; ++j) {
        int idx = t + 256 * j;              // 0..1023
        int rr = idx >> 7, l = idx & 127;
        lat[rr][l] = latent[(size_t)(b0 + rr) * 128 + l];
    }
    __syncthreads();
    const int o = t;
    float acc[8];
    float bbv = bb[o];
#pragma unroll
    for (int rr = 0; rr < 8; ++rr) acc[rr] = bbv;
    for (int l = 0; l < 128; ++l) {
        float w = Wb[l * 256 + o];
#pragma unroll
        for (int rr = 0; rr < 8; ++rr) acc[rr] += lat[rr][l] * w;
    }
#pragma unroll
    for (int rr = 0; rr < 8; ++rr) out[(size_t)(b0 + rr) * 256 + o] = acc[rr];
}

// ---------------- K4: main GEMM. Block: 128 rows x 256 cols, split-K=8 over slabs.
// A (x) in LDS (swizzled, loaded once, barrier-free K loop); B streamed in packed
// fragment order (one coalesced 1KB load per wave per fragment).
// Grid 512 -> 2 blocks/CU (LDS 2x64KB, VGPR<=256) -> 2 waves/SIMD for latency hiding.
__global__ __launch_bounds__(256, 2) void k_gemm(const _Float16* __restrict__ Bp,
                                                 const _Float16* __restrict__ Xh,
                                                 const _Float16* __restrict__ LT,
                                                 float* __restrict__ out) {
    __shared__ _Float16 Xs[128 * 256];      // 64 KB

    const int bid   = blockIdx.x;           // 512 blocks
    const int m_blk = bid >> 3;
    const int ks    = bid & 7;              // bid%8 == ks -> each XCD owns one k-split's B slice
    const int m0    = m_blk * 128;
    const int slab0 = (ks == 0) ? 0 : 17 + 16 * (ks - 1);
    const int nslab = (ks == 0) ? 17 : 16;  // 17 + 7*16 = 129

    const int tid = threadIdx.x, wid = tid >> 6, lane = tid & 63;
    const int l32 = lane & 31, khalf = lane >> 5;

    // ---- stage X tile into LDS with 16B-granule XOR swizzle (granule g stored at slot g^(m&7))
    for (int j = 0; j < 16; ++j) {
        int G = j * 256 + tid;              // 4096 granules total
        int m = G >> 5, gp = G & 31;
        int g = gp ^ (m & 7);
        h8 v = *(const h8*)(Xh + (size_t)(m0 + m) * IN_N + g * 8);
        *(h8*)(Xs + m * IN_N + gp * 8) = v;
    }
    __syncthreads();

    // per-lane rows (A side): m = t*32 + l32
    int mrow[4], m7[4], pbase[4], m6[4];
#pragma unroll
    for (int t = 0; t < 4; ++t) {
        mrow[t]  = t * 32 + l32;
        m7[t]    = mrow[t] & 7;
        m6[t]    = m7[t] & 6;
        pbase[t] = mrow[t] * IN_N + (khalf ^ (m7[t] & 1)) * 8;
    }

    // latent scalars for this block's rows
    const _Float16* ltp = LT + (size_t)slab0 * BATCH + m0;
    _Float16 s_cur[4], s_nxt[4];
#pragma unroll
    for (int t = 0; t < 4; ++t) s_cur[t] = ltp[mrow[t]];

    // B pointers (packed layout): fragment for (wave col-tile nt, k-tile kt) at
    // Bp + ((nt*KT16 + kt)*64 + lane)*8  -- lane-contiguous 16B each.
    const _Float16* bp0 = Bp + ((size_t)((wid * 2 + 0) * KT16 + slab0 * 16) * 64 + lane) * 8;
    const _Float16* bp1 = Bp + ((size_t)((wid * 2 + 1) * KT16 + slab0 * 16) * 64 + lane) * 8;

    f16v acc[4][2];
#pragma unroll
    for (int t = 0; t < 4; ++t)
#pragma unroll
        for (int u = 0; u < 2; ++u)
#pragma unroll
            for (int r = 0; r < 16; ++r) acc[t][u][r] = 0.0f;

    for (int sl = 0; sl < nslab; ++sl) {
        if (sl) {
#pragma unroll
            for (int t = 0; t < 4; ++t) s_cur[t] = s_nxt[t];
        }
        if (sl + 1 < nslab) {
            const _Float16* p = ltp + (size_t)(sl + 1) * BATCH;
#pragma unroll
            for (int t = 0; t < 4; ++t) s_nxt[t] = p[mrow[t]];
        }
        h8 s8[4];
#pragma unroll
        for (int t = 0; t < 4; ++t) {
            _Float16 s = s_cur[t];
            s8[t][0]=s; s8[t][1]=s; s8[t][2]=s; s8[t][3]=s;
            s8[t][4]=s; s8[t][5]=s; s8[t][6]=s; s8[t][7]=s;
        }
        const _Float16* b0p = bp0 + (size_t)sl * (16 * 512);
        const _Float16* b1p = bp1 + (size_t)sl * (16 * 512);
#pragma unroll
        for (int ks16 = 0; ks16 < 16; ++ks16) {
            h8 b0 = *(const h8*)(b0p + ks16 * 512);
            h8 b1 = *(const h8*)(b1p + ks16 * 512);
            h8 a[4];
#pragma unroll
            for (int t = 0; t < 4; ++t) {
                int off = pbase[t] + ((ks16 * 2) ^ m6[t]) * 8;
                h8 xv = *(const h8*)(Xs + off);
                a[t] = xv * s8[t];
            }
#pragma unroll
            for (int t = 0; t < 4; ++t) {
                acc[t][0] = __builtin_amdgcn_mfma_f32_32x32x16_f16(a[t], b0, acc[t][0], 0, 0, 0);
                acc[t][1] = __builtin_amdgcn_mfma_f32_32x32x16_f16(a[t], b1, acc[t][1], 0, 0, 0);
            }
        }
    }

    // epilogue: atomically accumulate onto out (bias pre-written by k_bias).
    // Lanes 0..31 of each atomic op are 32 contiguous f32 -> 128B segments.
#pragma unroll
    for (int t = 0; t < 4; ++t) {
        int rowb = m0 + t * 32;
#pragma unroll
        for (int u = 0; u < 2; ++u) {
            int col = wid * 64 + u * 32 + l32;
#pragma unroll
            for (int r = 0; r < 16; ++r) {
                int row = rowb + (r & 3) + 8 * (r >> 2) + 4 * khalf;
                unsafeAtomicAdd(out + (size_t)row * OUT_N + col, acc[t][u][r]);
            }
        }
    }
}

extern "C" void kernel_launch(void* const* d_in, const int* in_sizes, int n_in,
                              void* d_out, int out_size, void* d_ws, size_t ws_size,
                              hipStream_t stream) {
    const float* x      = (const float*)d_in[0];
    const float* latent = (const float*)d_in[1];
    const float* Ww     = (const float*)d_in[2];
    const float* bw     = (const float*)d_in[3];
    const float* Wb     = (const float*)d_in[4];
    const float* bb     = (const float*)d_in[5];

    char* ws = (char*)d_ws;
    _Float16* Bp  = (_Float16*)(ws + WS_BP);
    _Float16* Xh  = (_Float16*)(ws + WS_XH);
    _Float16* LT  = (_Float16*)(ws + WS_LT);
    float*    out = (float*)d_out;

    k_transpose<<<dim3(516, 4), 256, 0, stream>>>(Ww, bw, Bp);
    k_convert<<<6176, 256, 0, stream>>>(x, latent, Xh, LT);
    k_bias<<<1024, 256, 0, stream>>>(latent, Wb, bb, out);
    k_gemm<<<512, 256, 0, stream>>>(Bp, Xh, LT, out);
}

// Round 2
// 291.224 us; speedup vs baseline: 1.5989x; 1.5989x over previous
//
#include <hip/hip_runtime.h>
#include <cstdint>
#include <cstddef>

#define BATCH  8192
#define IN_N   256
#define OUT_N  256
#define LAT_N  128
#define SLABS  129                 // 128 latent slabs + 1 bw slab
#define KT     (SLABS * IN_N)      // 33024 = total K in elements
#define KT16   (KT / 16)           // 2064 k-tiles of 16
#define SPLITK 4

typedef _Float16 h8 __attribute__((ext_vector_type(8)));
typedef _Float16 h4 __attribute__((ext_vector_type(4)));
typedef float    f16v __attribute__((ext_vector_type(16)));
typedef float    f4v  __attribute__((ext_vector_type(4)));

// ws layout (bytes) — identical total footprint to the proven 354us baseline (56,770,560 B)
#define WS_BP    0                 // packed B: 8 nt * 2064 kt * 64 lane * 8 halves * 2B = 16908288
#define WS_XH    16908288          // + 8192*256*2 = 4194304
#define WS_LT    21102592          // + 129*8192*2 = 2113536
#define WS_PARTS 23216128          // + 4 * 8192*256*4 = 33554432  -> total 56770560

// ---------------- K1: build B in MFMA-fragment-packed order.
// Bp[nt][kt16][lane][h]  (lane = kh*32 + n32, h = 0..7)
//   = W2T[o = nt*32 + n32][k = kt16*16 + kh*8 + h]
// where W2T[o][k] = k<32768 ? Ww[k*256+o] : bw[(k-32768)*256+o]
// A wave's B-fragment load in k_gemm is then one contiguous 1KB dwordx4.
__global__ void k_transpose(const float* __restrict__ Ww, const float* __restrict__ bw,
                            _Float16* __restrict__ Bp) {
    __shared__ float tile[64][65];
    const int k0 = blockIdx.x * 64;    // 516 tiles along k (516*64 = 33024)
    const int o0 = blockIdx.y * 64;    // 4 tiles along o
    const int t  = threadIdx.x;        // 256 threads
    const int c  = t & 63, r0 = t >> 6;
#pragma unroll
    for (int j = 0; j < 16; ++j) {
        int r = r0 + 4 * j;
        int k = k0 + r;
        float v;
        if (k < LAT_N * IN_N) v = Ww[(size_t)k * 256 + o0 + c];
        else                  v = bw[(size_t)(k - LAT_N * IN_N) * 256 + o0 + c];
        tile[r][c] = v;               // tile[k - k0][o - o0]
    }
    __syncthreads();
    // pack phase: 8 subtiles of [16k x 32o]; subtile st handled by threads st*32..st*32+31
    const int tl = t & 31, st = t >> 5;
    const int kt_l = st >> 1, nt_l = st & 1;
    const int nt   = blockIdx.y * 2 + nt_l;              // 0..7
    const int kt16 = blockIdx.x * 4 + kt_l;              // 0..2063
    _Float16* dst = Bp + ((size_t)(nt * KT16 + kt16) * 64) * 8;
#pragma unroll
    for (int kh = 0; kh < 2; ++kh) {
        h8 v;
#pragma unroll
        for (int h = 0; h < 8; ++h)
            v[h] = (_Float16)tile[kt_l * 16 + kh * 8 + h][nt_l * 32 + tl];
        *(h8*)(dst + (size_t)(kh * 32 + tl) * 8) = v;
    }
}

// ---------------- K2: x -> f16, latent -> LT[l][b] f16 (+ ones row l=128)
__global__ void k_convert(const float* __restrict__ x, const float* __restrict__ latent,
                          _Float16* __restrict__ Xh, _Float16* __restrict__ LT) {
    const int bid = blockIdx.x;
    if (bid < 2048) {                       // x: 2M elems, 4 per thread
        int i = (bid * 256 + threadIdx.x) * 4;
        float4 v = *(const float4*)(x + i);
        h4 o;
        o[0] = (_Float16)v.x; o[1] = (_Float16)v.y;
        o[2] = (_Float16)v.z; o[3] = (_Float16)v.w;
        *(h4*)(Xh + i) = o;
    } else if (bid < 2048 + 4096) {         // latent transpose: 1M elems
        int i = (bid - 2048) * 256 + threadIdx.x;
        int b = i >> 7, l = i & 127;
        LT[(size_t)l * BATCH + b] = (_Float16)latent[i];
    } else {                                // ones row: 8192 elems
        int b = (bid - 2048 - 4096) * 256 + threadIdx.x;
        LT[(size_t)LAT_N * BATCH + b] = (_Float16)1.0f;
    }
}

// ---------------- K3: part0[b][o] = latent[b]·Wb[:,o] + bb[o]  (bias pre-folded into split-0 partial)
__global__ void k_bias(const float* __restrict__ latent, const float* __restrict__ Wb,
                       const float* __restrict__ bb, float* __restrict__ part0) {
    __shared__ float lat[8][128];
    const int b0 = blockIdx.x * 8;          // 1024 blocks
    const int t = threadIdx.x;
#pragma unroll
    for (int j = 0; j < 4; ++j) {
        int idx = t + 256 * j;              // 0..1023
        int rr = idx >> 7, l = idx & 127;
        lat[rr][l] = latent[(size_t)(b0 + rr) * 128 + l];
    }
    __syncthreads();
    const int o = t;
    float acc[8];
    float bbv = bb[o];
#pragma unroll
    for (int rr = 0; rr < 8; ++rr) acc[rr] = bbv;
    for (int l = 0; l < 128; ++l) {
        float w = Wb[l * 256 + o];
#pragma unroll
        for (int rr = 0; rr < 8; ++rr) acc[rr] += lat[rr][l] * w;
    }
#pragma unroll
    for (int rr = 0; rr < 8; ++rr) part0[(size_t)(b0 + rr) * 256 + o] = acc[rr];
}

// ---------------- K4: main GEMM. Block: 64 rows x 256 cols, split-K=4 over slabs.
// Grid 512 = 128 m-blocks x 4 k-splits -> 2 blocks/CU (LDS 2x32KB, VGPR<=256 via bounds)
// -> 2 waves/SIMD so one wave's MFMA hides the other's loads.
// A (x) in LDS (swizzled, loaded once, barrier-free K loop); B streamed in packed
// fragment order (one coalesced 1KB wave-load per fragment). ks = bid&3 keeps each
// XCD's resident blocks on a single 4.2MB B-slice (~its private L2).
__global__ __launch_bounds__(256, 2) void k_gemm(const _Float16* __restrict__ Bp,
                                                 const _Float16* __restrict__ Xh,
                                                 const _Float16* __restrict__ LT,
                                                 float* __restrict__ parts) {
    __shared__ _Float16 Xs[64 * 256];       // 32 KB

    const int bid   = blockIdx.x;           // 512 blocks
    const int m_blk = bid >> 2;             // 0..127
    const int ks    = bid & 3;
    const int m0    = m_blk * 64;
    const int slab0 = (ks == 0) ? 0 : 33 + 32 * (ks - 1);
    const int nslab = (ks == 0) ? 33 : 32;  // 33 + 3*32 = 129

    const int tid = threadIdx.x, wid = tid >> 6, lane = tid & 63;
    const int l32 = lane & 31, khalf = lane >> 5;

    // ---- stage X tile into LDS with 16B-granule XOR swizzle (granule g stored at slot g^(m&7))
    for (int j = 0; j < 8; ++j) {
        int G = j * 256 + tid;              // 2048 granules total
        int m = G >> 5, gp = G & 31;
        int g = gp ^ (m & 7);
        h8 v = *(const h8*)(Xh + (size_t)(m0 + m) * IN_N + g * 8);
        *(h8*)(Xs + m * IN_N + gp * 8) = v;
    }
    __syncthreads();

    // per-lane rows (A side): m = t*32 + l32, t in {0,1}
    int mrow[2], m7[2], pbase[2], m6[2];
#pragma unroll
    for (int t = 0; t < 2; ++t) {
        mrow[t]  = t * 32 + l32;
        m7[t]    = mrow[t] & 7;
        m6[t]    = m7[t] & 6;
        pbase[t] = mrow[t] * IN_N + (khalf ^ (m7[t] & 1)) * 8;
    }

    // latent scalars for this block's rows
    const _Float16* ltp = LT + (size_t)slab0 * BATCH + m0;
    _Float16 s_cur[2], s_nxt[2];
#pragma unroll
    for (int t = 0; t < 2; ++t) s_cur[t] = ltp[mrow[t]];

    // B pointers (packed layout): fragment for (col-tile nt, k-tile kt) at
    // Bp + ((nt*KT16 + kt)*64 + lane)*8  -- lane-contiguous 16B each.
    const _Float16* bp0 = Bp + ((size_t)((wid * 2 + 0) * KT16 + slab0 * 16) * 64 + lane) * 8;
    const _Float16* bp1 = Bp + ((size_t)((wid * 2 + 1) * KT16 + slab0 * 16) * 64 + lane) * 8;

    f16v acc[2][2];
#pragma unroll
    for (int t = 0; t < 2; ++t)
#pragma unroll
        for (int u = 0; u < 2; ++u)
#pragma unroll
            for (int r = 0; r < 16; ++r) acc[t][u][r] = 0.0f;

    for (int sl = 0; sl < nslab; ++sl) {
        if (sl) {
#pragma unroll
            for (int t = 0; t < 2; ++t) s_cur[t] = s_nxt[t];
        }
        if (sl + 1 < nslab) {
            const _Float16* p = ltp + (size_t)(sl + 1) * BATCH;
#pragma unroll
            for (int t = 0; t < 2; ++t) s_nxt[t] = p[mrow[t]];
        }
        h8 s8[2];
#pragma unroll
        for (int t = 0; t < 2; ++t) {
            _Float16 s = s_cur[t];
            s8[t][0]=s; s8[t][1]=s; s8[t][2]=s; s8[t][3]=s;
            s8[t][4]=s; s8[t][5]=s; s8[t][6]=s; s8[t][7]=s;
        }
        const _Float16* b0p = bp0 + (size_t)sl * (16 * 512);
        const _Float16* b1p = bp1 + (size_t)sl * (16 * 512);
#pragma unroll
        for (int ks16 = 0; ks16 < 16; ++ks16) {
            h8 b0 = *(const h8*)(b0p + ks16 * 512);
            h8 b1 = *(const h8*)(b1p + ks16 * 512);
            h8 a[2];
#pragma unroll
            for (int t = 0; t < 2; ++t) {
                int off = pbase[t] + ((ks16 * 2) ^ m6[t]) * 8;
                h8 xv = *(const h8*)(Xs + off);
                a[t] = xv * s8[t];
            }
#pragma unroll
            for (int t = 0; t < 2; ++t) {
                acc[t][0] = __builtin_amdgcn_mfma_f32_32x32x16_f16(a[t], b0, acc[t][0], 0, 0, 0);
                acc[t][1] = __builtin_amdgcn_mfma_f32_32x32x16_f16(a[t], b1, acc[t][1], 0, 0, 0);
            }
        }
    }

    // epilogue: write partials; split 0 accumulates onto pre-written bias
    float* dst = parts + (size_t)ks * ((size_t)BATCH * OUT_N);
#pragma unroll
    for (int t = 0; t < 2; ++t) {
        int rowb = m0 + t * 32;
#pragma unroll
        for (int u = 0; u < 2; ++u) {
            int col = wid * 64 + u * 32 + l32;
#pragma unroll
            for (int r = 0; r < 16; ++r) {
                int row = rowb + (r & 3) + 8 * (r >> 2) + 4 * khalf;
                size_t off = (size_t)row * OUT_N + col;
                float v = acc[t][u][r];
                if (ks == 0) dst[off] += v;
                else         dst[off] = v;
            }
        }
    }
}

// ---------------- K5: out = sum of 4 partials
__global__ void k_reduce(const float* __restrict__ parts, float* __restrict__ out) {
    int i = (blockIdx.x * 256 + threadIdx.x) * 4;
    f4v s = *(const f4v*)(parts + i);
    s += *(const f4v*)(parts + 2097152 + i);
    s += *(const f4v*)(parts + 2 * 2097152 + i);
    s += *(const f4v*)(parts + 3 * 2097152 + i);
    *(f4v*)(out + i) = s;
}

extern "C" void kernel_launch(void* const* d_in, const int* in_sizes, int n_in,
                              void* d_out, int out_size, void* d_ws, size_t ws_size,
                              hipStream_t stream) {
    const float* x      = (const float*)d_in[0];
    const float* latent = (const float*)d_in[1];
    const float* Ww     = (const float*)d_in[2];
    const float* bw     = (const float*)d_in[3];
    const float* Wb     = (const float*)d_in[4];
    const float* bb     = (const float*)d_in[5];

    char* ws = (char*)d_ws;
    _Float16* Bp    = (_Float16*)(ws + WS_BP);
    _Float16* Xh    = (_Float16*)(ws + WS_XH);
    _Float16* LT    = (_Float16*)(ws + WS_LT);
    float*    parts = (float*)(ws + WS_PARTS);
    float*    out   = (float*)d_out;

    k_transpose<<<dim3(516, 4), 256, 0, stream>>>(Ww, bw, Bp);
    k_convert<<<6176, 256, 0, stream>>>(x, latent, Xh, LT);
    k_bias<<<1024, 256, 0, stream>>>(latent, Wb, bb, parts + 0);
    k_gemm<<<512, 256, 0, stream>>>(Bp, Xh, LT, parts);
    k_reduce<<<2048, 256, 0, stream>>>(parts, out);
}